// Round 1
// baseline (554.378 us; speedup 1.0000x reference)
//
#include <hip/hip_runtime.h>
#include <hip/hip_bf16.h>
#include <stdint.h>

#define S_LEN 2048
#define E_DIM 1024
#define NHEAD 8
#define HDIM 128
#define SCALE 0.022097086912079608f  // 1/sqrt(2048)

typedef __attribute__((ext_vector_type(8))) short short8;
typedef __attribute__((ext_vector_type(4))) float f32x4;

__device__ __forceinline__ ushort f2bf(float f) {
  __hip_bfloat16 h = __float2bfloat16(f);
  return __builtin_bit_cast(ushort, h);
}

__device__ __forceinline__ void gload_lds16(const void* g, void* l) {
  __builtin_amdgcn_global_load_lds(
      (const __attribute__((address_space(1))) uint32_t*)g,
      (__attribute__((address_space(3))) uint32_t*)l, 16, 0, 0);
}

// ---------------- K1a: cast X fp32 -> bf16 ----------------
__global__ void cast_x_kernel(const float* __restrict__ X, ushort* __restrict__ Xb) {
  int i = (blockIdx.x * 256 + threadIdx.x) * 4;
  float4 v = *(const float4*)(X + i);
  ushort4 o;
  o.x = f2bf(v.x); o.y = f2bf(v.y); o.z = f2bf(v.z); o.w = f2bf(v.w);
  *(ushort4*)(Xb + i) = o;
}

// ---------------- K1b: transpose + cast W (K x N) -> WT (N x K) bf16 ----------------
__global__ void transpose_w_kernel(const float* __restrict__ W0, const float* __restrict__ W1,
                                   const float* __restrict__ W2, ushort* __restrict__ WT) {
  const float* W = blockIdx.z == 0 ? W0 : (blockIdx.z == 1 ? W1 : W2);
  ushort* out = WT + (size_t)blockIdx.z * E_DIM * E_DIM;
  int tk = blockIdx.x * 64, tn = blockIdx.y * 64;
  __shared__ float t[64][65];
  int tid = threadIdx.x;
  int rbase = tid >> 4;        // 0..15
  int cc4 = (tid & 15) * 4;    // 0..60
#pragma unroll
  for (int q = 0; q < 4; q++) {
    int row = q * 16 + rbase;
    float4 v = *(const float4*)(W + (size_t)(tk + row) * E_DIM + tn + cc4);
    t[row][cc4] = v.x; t[row][cc4 + 1] = v.y; t[row][cc4 + 2] = v.z; t[row][cc4 + 3] = v.w;
  }
  __syncthreads();
#pragma unroll
  for (int q = 0; q < 4; q++) {
    int row = q * 16 + rbase;  // n-local
    ushort4 o;
    o.x = f2bf(t[cc4 + 0][row]);
    o.y = f2bf(t[cc4 + 1][row]);
    o.z = f2bf(t[cc4 + 2][row]);
    o.w = f2bf(t[cc4 + 3][row]);
    *(ushort4*)(out + (size_t)(tn + row) * E_DIM + tk + cc4) = o;
  }
}

// ---------------- K2: QKV GEMM: [4096x1024] @ WT[p] + bias -> Qb/Kb (SxE) bf16, V transposed ----------------
__global__ __launch_bounds__(256)
void qkv_gemm_kernel(const ushort* __restrict__ Xb, const ushort* __restrict__ WT,
                     const float* __restrict__ bq, const float* __restrict__ bk,
                     const float* __restrict__ bv,
                     ushort* __restrict__ Qb, ushort* __restrict__ Kb, ushort* __restrict__ Vt) {
  int p = blockIdx.z;
  const ushort* Wp = WT + (size_t)p * E_DIM * E_DIM;
  const float* bias = (p == 0) ? bq : ((p == 1) ? bk : bv);
  int tm = blockIdx.x, tn = blockIdx.y;
  __shared__ ushort lA[128 * 64];
  __shared__ ushort lB[128 * 64];
  int tid = threadIdx.x, lane = tid & 63, w = tid >> 6;
  int wr = (w >> 1) * 64, wc = (w & 1) * 64;
  f32x4 acc[4][4] = {};
  const char* gA = (const char*)(Xb + (size_t)(tm * 128) * E_DIM);
  const char* gB = (const char*)(Wp + (size_t)(tn * 128) * E_DIM);
  char* sA = (char*)lA;
  char* sB = (char*)lB;
  for (int ks = 0; ks < E_DIM / 64; ks++) {
    int k0 = ks * 64;
#pragma unroll
    for (int rr = 0; rr < 4; rr++) {
      int c = rr * 256 + tid;
      int row = c >> 3, cc = c & 7;
      int sc = cc ^ (row & 7);  // inverse-swizzled global source (rule #21)
      size_t goff = ((size_t)row * E_DIM + k0 + sc * 8) * 2;
      int loff = (rr * 256 + (w << 6)) * 16;
      gload_lds16(gA + goff, sA + loff);
      gload_lds16(gB + goff, sB + loff);
    }
    __syncthreads();
#pragma unroll
    for (int kk = 0; kk < 2; kk++) {
      short8 af[4], bfr[4];
#pragma unroll
      for (int m = 0; m < 4; m++) {
        int row = wr + m * 16 + (lane & 15);
        int ch = (kk * 4 + (lane >> 4)) ^ (row & 7);
        af[m] = *(const short8*)(sA + row * 128 + ch * 16);
      }
#pragma unroll
      for (int n = 0; n < 4; n++) {
        int row = wc + n * 16 + (lane & 15);
        int ch = (kk * 4 + (lane >> 4)) ^ (row & 7);
        bfr[n] = *(const short8*)(sB + row * 128 + ch * 16);
      }
#pragma unroll
      for (int m = 0; m < 4; m++)
#pragma unroll
        for (int n = 0; n < 4; n++)
          acc[m][n] = __builtin_amdgcn_mfma_f32_16x16x32_bf16(af[m], bfr[n], acc[m][n], 0, 0, 0);
    }
    __syncthreads();
  }
#pragma unroll
  for (int m = 0; m < 4; m++) {
#pragma unroll
    for (int ri = 0; ri < 4; ri++) {
      int rg = tm * 128 + wr + m * 16 + (lane >> 4) * 4 + ri;
      float bsv = bias[rg & (S_LEN - 1)];
#pragma unroll
      for (int n = 0; n < 4; n++) {
        int cg = tn * 128 + wc + n * 16 + (lane & 15);
        ushort o = f2bf(acc[m][n][ri] + bsv);
        if (p == 0) {
          Qb[(size_t)rg * E_DIM + cg] = o;
        } else if (p == 1) {
          Kb[(size_t)rg * E_DIM + cg] = o;
        } else {
          int bb = rg >> 11, s2 = rg & (S_LEN - 1), hh = cg >> 7, dd = cg & (HDIM - 1);
          Vt[(((size_t)(bb * NHEAD + hh)) * HDIM + dd) * S_LEN + s2] = o;
        }
      }
    }
  }
}

// ---------------- K3: attn = Q K^T * scale + residual (per head), fp32 out ----------------
__global__ __launch_bounds__(256)
void attn_gemm_kernel(const ushort* __restrict__ Qb, const ushort* __restrict__ Kb,
                      const float* __restrict__ resid, float* __restrict__ attn_out) {
  int tm = blockIdx.x, tn = blockIdx.y, bh = blockIdx.z;
  int b = bh >> 3, h = bh & 7;
  __shared__ ushort lA[128 * 64];
  __shared__ ushort lB[128 * 64];
  int tid = threadIdx.x, lane = tid & 63, w = tid >> 6;
  int wr = (w >> 1) * 64, wc = (w & 1) * 64;
  f32x4 acc[4][4] = {};
  const char* gA = (const char*)(Qb + ((size_t)(b * S_LEN + tm * 128)) * E_DIM + h * HDIM);
  const char* gB = (const char*)(Kb + ((size_t)(b * S_LEN + tn * 128)) * E_DIM + h * HDIM);
  char* sA = (char*)lA;
  char* sB = (char*)lB;
  for (int ks = 0; ks < 2; ks++) {
    int k0 = ks * 64;
#pragma unroll
    for (int rr = 0; rr < 4; rr++) {
      int c = rr * 256 + tid;
      int row = c >> 3, cc = c & 7;
      int sc = cc ^ (row & 7);
      size_t goff = ((size_t)row * E_DIM + k0 + sc * 8) * 2;
      int loff = (rr * 256 + (w << 6)) * 16;
      gload_lds16(gA + goff, sA + loff);
      gload_lds16(gB + goff, sB + loff);
    }
    __syncthreads();
#pragma unroll
    for (int kk = 0; kk < 2; kk++) {
      short8 af[4], bfr[4];
#pragma unroll
      for (int m = 0; m < 4; m++) {
        int row = wr + m * 16 + (lane & 15);
        int ch = (kk * 4 + (lane >> 4)) ^ (row & 7);
        af[m] = *(const short8*)(sA + row * 128 + ch * 16);
      }
#pragma unroll
      for (int n = 0; n < 4; n++) {
        int row = wc + n * 16 + (lane & 15);
        int ch = (kk * 4 + (lane >> 4)) ^ (row & 7);
        bfr[n] = *(const short8*)(sB + row * 128 + ch * 16);
      }
#pragma unroll
      for (int m = 0; m < 4; m++)
#pragma unroll
        for (int n = 0; n < 4; n++)
          acc[m][n] = __builtin_amdgcn_mfma_f32_16x16x32_bf16(af[m], bfr[n], acc[m][n], 0, 0, 0);
    }
    __syncthreads();
  }
  float* outp = attn_out + (size_t)bh * S_LEN * S_LEN;
#pragma unroll
  for (int m = 0; m < 4; m++) {
#pragma unroll
    for (int ri = 0; ri < 4; ri++) {
      int sg = tm * 128 + wr + m * 16 + (lane >> 4) * 4 + ri;
#pragma unroll
      for (int n = 0; n < 4; n++) {
        int tg = tn * 128 + wc + n * 16 + (lane & 15);
        outp[(size_t)sg * S_LEN + tg] = acc[m][n][ri] * SCALE + resid[(size_t)sg * S_LEN + tg];
      }
    }
  }
}

// ---------------- K4: effect = (exp(attn)*Wepi / rowsum(exp(attn))) @ V + bo ----------------
__global__ __launch_bounds__(256)
void pv_gemm_kernel(const float* __restrict__ attn, const float* __restrict__ Wepi,
                    const ushort* __restrict__ Vt, const float* __restrict__ bo,
                    float* __restrict__ effect) {
  int tm = blockIdx.x, bh = blockIdx.y;
  int b = bh >> 3, h = bh & 7;
  __shared__ ushort lA[128 * 64];
  __shared__ ushort lB[128 * 64];
  __shared__ float l_lds[256];
  int tid = threadIdx.x, lane = tid & 63, w = tid >> 6;
  int wr = (w >> 1) * 64, wc = (w & 1) * 64;
  f32x4 acc[4][4] = {};
  float lsum = 0.f;
  int r = tid >> 1, half = tid & 1;
  const float* aRow = attn + (size_t)bh * S_LEN * S_LEN + (size_t)(tm * 128 + r) * S_LEN + half * 32;
  const float* wRow = Wepi + (size_t)(tm * 128 + r) * S_LEN + half * 32;
  const char* gB = (const char*)(Vt + (size_t)bh * HDIM * S_LEN);
  char* sA = (char*)lA;
  char* sB = (char*)lB;
  for (int ks = 0; ks < S_LEN / 64; ks++) {
    int t0 = ks * 64;
#pragma unroll
    for (int rr = 0; rr < 4; rr++) {
      int c = rr * 256 + tid;
      int row = c >> 3, cc = c & 7;
      int sc = cc ^ (row & 7);
      gload_lds16(gB + ((size_t)row * S_LEN + t0 + sc * 8) * 2, sB + (rr * 256 + (w << 6)) * 16);
    }
    // compute score tile elems into lA (reg-staged, swizzled ds_write)
#pragma unroll
    for (int cgrp = 0; cgrp < 4; cgrp++) {
      float4 a0 = *(const float4*)(aRow + t0 + cgrp * 8);
      float4 a1 = *(const float4*)(aRow + t0 + cgrp * 8 + 4);
      float4 w0 = *(const float4*)(wRow + t0 + cgrp * 8);
      float4 w1 = *(const float4*)(wRow + t0 + cgrp * 8 + 4);
      float e0 = __expf(a0.x), e1 = __expf(a0.y), e2 = __expf(a0.z), e3 = __expf(a0.w);
      float e4 = __expf(a1.x), e5 = __expf(a1.y), e6 = __expf(a1.z), e7 = __expf(a1.w);
      lsum += (e0 + e1 + e2 + e3) + (e4 + e5 + e6 + e7);
      short8 pk;
      pk[0] = (short)f2bf(e0 * w0.x); pk[1] = (short)f2bf(e1 * w0.y);
      pk[2] = (short)f2bf(e2 * w0.z); pk[3] = (short)f2bf(e3 * w0.w);
      pk[4] = (short)f2bf(e4 * w1.x); pk[5] = (short)f2bf(e5 * w1.y);
      pk[6] = (short)f2bf(e6 * w1.z); pk[7] = (short)f2bf(e7 * w1.w);
      int ch = (half * 4 + cgrp) ^ (r & 7);
      *(short8*)(sA + r * 128 + ch * 16) = pk;
    }
    __syncthreads();
#pragma unroll
    for (int kk = 0; kk < 2; kk++) {
      short8 af[4], bfr[4];
#pragma unroll
      for (int m = 0; m < 4; m++) {
        int row = wr + m * 16 + (lane & 15);
        int ch = (kk * 4 + (lane >> 4)) ^ (row & 7);
        af[m] = *(const short8*)(sA + row * 128 + ch * 16);
      }
#pragma unroll
      for (int n = 0; n < 4; n++) {
        int row = wc + n * 16 + (lane & 15);
        int ch = (kk * 4 + (lane >> 4)) ^ (row & 7);
        bfr[n] = *(const short8*)(sB + row * 128 + ch * 16);
      }
#pragma unroll
      for (int m = 0; m < 4; m++)
#pragma unroll
        for (int n = 0; n < 4; n++)
          acc[m][n] = __builtin_amdgcn_mfma_f32_16x16x32_bf16(af[m], bfr[n], acc[m][n], 0, 0, 0);
    }
    __syncthreads();
  }
  l_lds[tid] = lsum;
  __syncthreads();
#pragma unroll
  for (int m = 0; m < 4; m++) {
#pragma unroll
    for (int ri = 0; ri < 4; ri++) {
      int rl = wr + m * 16 + (lane >> 4) * 4 + ri;
      int sg = tm * 128 + rl;
      float linv = 1.0f / (l_lds[2 * rl] + l_lds[2 * rl + 1]);
      float bov = bo[sg];
#pragma unroll
      for (int n = 0; n < 4; n++) {
        int dg = wc + n * 16 + (lane & 15);
        effect[((size_t)(b * S_LEN + sg)) * E_DIM + h * HDIM + dg] = acc[m][n][ri] * linv + bov;
      }
    }
  }
}

extern "C" void kernel_launch(void* const* d_in, const int* in_sizes, int n_in,
                              void* d_out, int out_size, void* d_ws, size_t ws_size,
                              hipStream_t stream) {
  const float* X    = (const float*)d_in[0];
  const float* resd = (const float*)d_in[1];
  const float* Wq   = (const float*)d_in[2];
  const float* Wk   = (const float*)d_in[3];
  const float* Wv   = (const float*)d_in[4];
  const float* Wepi = (const float*)d_in[5];
  const float* bq   = (const float*)d_in[6];
  const float* bk   = (const float*)d_in[7];
  const float* bv   = (const float*)d_in[8];
  const float* bo   = (const float*)d_in[9];

  float* effect = (float*)d_out;
  float* attn   = (float*)d_out + (size_t)2 * S_LEN * E_DIM;  // 4,194,304 floats of effect first

  char* ws = (char*)d_ws;
  ushort* Xb = (ushort*)(ws);                 //  8,388,608 B
  ushort* WT = (ushort*)(ws + 8388608);       //  6,291,456 B
  ushort* Qb = (ushort*)(ws + 14680064);      //  8,388,608 B
  ushort* Kb = (ushort*)(ws + 23068672);      //  8,388,608 B
  ushort* Vt = (ushort*)(ws + 31457280);      //  8,388,608 B  (total ~38 MB)

  hipLaunchKernelGGL(cast_x_kernel, dim3(4096), dim3(256), 0, stream, X, Xb);
  hipLaunchKernelGGL(transpose_w_kernel, dim3(16, 16, 3), dim3(256), 0, stream, Wq, Wk, Wv, WT);
  hipLaunchKernelGGL(qkv_gemm_kernel, dim3(32, 8, 3), dim3(256), 0, stream,
                     Xb, WT, bq, bk, bv, Qb, Kb, Vt);
  hipLaunchKernelGGL(attn_gemm_kernel, dim3(16, 16, 16), dim3(256), 0, stream,
                     Qb, Kb, resd, attn);
  hipLaunchKernelGGL(pv_gemm_kernel, dim3(16, 16), dim3(256), 0, stream,
                     attn, Wepi, Vt, bo, effect);
}

// Round 2
// 541.679 us; speedup vs baseline: 1.0234x; 1.0234x over previous
//
#include <hip/hip_runtime.h>
#include <hip/hip_bf16.h>
#include <stdint.h>

#define S_LEN 2048
#define E_DIM 1024
#define NHEAD 8
#define HDIM 128
#define SCALE 0.022097086912079608f  // 1/sqrt(2048)

typedef __attribute__((ext_vector_type(8))) short short8;
typedef __attribute__((ext_vector_type(4))) float f32x4;

__device__ __forceinline__ ushort f2bf(float f) {
  __hip_bfloat16 h = __float2bfloat16(f);
  return __builtin_bit_cast(ushort, h);
}

__device__ __forceinline__ void gload_lds16(const void* g, void* l) {
  __builtin_amdgcn_global_load_lds(
      (const __attribute__((address_space(1))) uint32_t*)g,
      (__attribute__((address_space(3))) uint32_t*)l, 16, 0, 0);
}

// ---------------- K1a: cast X fp32 -> bf16 ----------------
__global__ void cast_x_kernel(const float* __restrict__ X, ushort* __restrict__ Xb) {
  int i = (blockIdx.x * 256 + threadIdx.x) * 4;
  float4 v = *(const float4*)(X + i);
  ushort4 o;
  o.x = f2bf(v.x); o.y = f2bf(v.y); o.z = f2bf(v.z); o.w = f2bf(v.w);
  *(ushort4*)(Xb + i) = o;
}

// ---------------- K1b: transpose + cast W (K x N) -> WT (N x K) bf16 ----------------
__global__ void transpose_w_kernel(const float* __restrict__ W0, const float* __restrict__ W1,
                                   const float* __restrict__ W2, ushort* __restrict__ WT) {
  const float* W = blockIdx.z == 0 ? W0 : (blockIdx.z == 1 ? W1 : W2);
  ushort* out = WT + (size_t)blockIdx.z * E_DIM * E_DIM;
  int tk = blockIdx.x * 64, tn = blockIdx.y * 64;
  __shared__ float t[64][65];
  int tid = threadIdx.x;
  int rbase = tid >> 4;        // 0..15
  int cc4 = (tid & 15) * 4;    // 0..60
#pragma unroll
  for (int q = 0; q < 4; q++) {
    int row = q * 16 + rbase;
    float4 v = *(const float4*)(W + (size_t)(tk + row) * E_DIM + tn + cc4);
    t[row][cc4] = v.x; t[row][cc4 + 1] = v.y; t[row][cc4 + 2] = v.z; t[row][cc4 + 3] = v.w;
  }
  __syncthreads();
#pragma unroll
  for (int q = 0; q < 4; q++) {
    int row = q * 16 + rbase;  // n-local
    ushort4 o;
    o.x = f2bf(t[cc4 + 0][row]);
    o.y = f2bf(t[cc4 + 1][row]);
    o.z = f2bf(t[cc4 + 2][row]);
    o.w = f2bf(t[cc4 + 3][row]);
    *(ushort4*)(out + (size_t)(tn + row) * E_DIM + tk + cc4) = o;
  }
}

// ---------------- K2: QKV GEMM: [4096x1024] @ WT[p] + bias -> Qb/Kb (SxE) bf16, V transposed ----------------
__global__ __launch_bounds__(256)
void qkv_gemm_kernel(const ushort* __restrict__ Xb, const ushort* __restrict__ WT,
                     const float* __restrict__ bq, const float* __restrict__ bk,
                     const float* __restrict__ bv,
                     ushort* __restrict__ Qb, ushort* __restrict__ Kb, ushort* __restrict__ Vt) {
  int p = blockIdx.z;
  const ushort* Wp = WT + (size_t)p * E_DIM * E_DIM;
  const float* bias = (p == 0) ? bq : ((p == 1) ? bk : bv);
  int tm = blockIdx.x, tn = blockIdx.y;
  __shared__ ushort lA[128 * 64];
  __shared__ ushort lB[128 * 64];
  int tid = threadIdx.x, lane = tid & 63, w = tid >> 6;
  int wr = (w >> 1) * 64, wc = (w & 1) * 64;
  f32x4 acc[4][4] = {};
  const char* gA = (const char*)(Xb + (size_t)(tm * 128) * E_DIM);
  const char* gB = (const char*)(Wp + (size_t)(tn * 128) * E_DIM);
  char* sA = (char*)lA;
  char* sB = (char*)lB;
  for (int ks = 0; ks < E_DIM / 64; ks++) {
    int k0 = ks * 64;
#pragma unroll
    for (int rr = 0; rr < 4; rr++) {
      int c = rr * 256 + tid;
      int row = c >> 3, cc = c & 7;
      int sc = cc ^ (row & 7);  // inverse-swizzled global source (rule #21)
      size_t goff = ((size_t)row * E_DIM + k0 + sc * 8) * 2;
      int loff = (rr * 256 + (w << 6)) * 16;
      gload_lds16(gA + goff, sA + loff);
      gload_lds16(gB + goff, sB + loff);
    }
    __syncthreads();
#pragma unroll
    for (int kk = 0; kk < 2; kk++) {
      short8 af[4], bfr[4];
#pragma unroll
      for (int m = 0; m < 4; m++) {
        int row = wr + m * 16 + (lane & 15);
        int ch = (kk * 4 + (lane >> 4)) ^ (row & 7);
        af[m] = *(const short8*)(sA + row * 128 + ch * 16);
      }
#pragma unroll
      for (int n = 0; n < 4; n++) {
        int row = wc + n * 16 + (lane & 15);
        int ch = (kk * 4 + (lane >> 4)) ^ (row & 7);
        bfr[n] = *(const short8*)(sB + row * 128 + ch * 16);
      }
#pragma unroll
      for (int m = 0; m < 4; m++)
#pragma unroll
        for (int n = 0; n < 4; n++)
          acc[m][n] = __builtin_amdgcn_mfma_f32_16x16x32_bf16(af[m], bfr[n], acc[m][n], 0, 0, 0);
    }
    __syncthreads();
  }
#pragma unroll
  for (int m = 0; m < 4; m++) {
#pragma unroll
    for (int ri = 0; ri < 4; ri++) {
      int rg = tm * 128 + wr + m * 16 + (lane >> 4) * 4 + ri;
      float bsv = bias[rg & (S_LEN - 1)];
#pragma unroll
      for (int n = 0; n < 4; n++) {
        int cg = tn * 128 + wc + n * 16 + (lane & 15);
        ushort o = f2bf(acc[m][n][ri] + bsv);
        if (p == 0) {
          Qb[(size_t)rg * E_DIM + cg] = o;
        } else if (p == 1) {
          Kb[(size_t)rg * E_DIM + cg] = o;
        } else {
          int bb = rg >> 11, s2 = rg & (S_LEN - 1), hh = cg >> 7, dd = cg & (HDIM - 1);
          Vt[(((size_t)(bb * NHEAD + hh)) * HDIM + dd) * S_LEN + s2] = o;
        }
      }
    }
  }
}

// ---------------- K3: attn = Q K^T * scale + residual; also P = exp(attn)*Wepi (bf16) + row-sum partials ----------------
__global__ __launch_bounds__(256)
void attn_gemm_kernel(const ushort* __restrict__ Qb, const ushort* __restrict__ Kb,
                      const float* __restrict__ resid, const float* __restrict__ Wepi,
                      float* __restrict__ attn_out, ushort* __restrict__ P,
                      float* __restrict__ rsum) {
  int tm = blockIdx.x, tn = blockIdx.y, bh = blockIdx.z;
  int b = bh >> 3, h = bh & 7;
  __shared__ ushort lA[128 * 64];
  __shared__ ushort lB[128 * 64];
  __shared__ float rs_lds[128][2];
  int tid = threadIdx.x, lane = tid & 63, w = tid >> 6;
  int wr = (w >> 1) * 64, wc = (w & 1) * 64;
  f32x4 acc[4][4] = {};
  const char* gA = (const char*)(Qb + ((size_t)(b * S_LEN + tm * 128)) * E_DIM + h * HDIM);
  const char* gB = (const char*)(Kb + ((size_t)(b * S_LEN + tn * 128)) * E_DIM + h * HDIM);
  char* sA = (char*)lA;
  char* sB = (char*)lB;
  for (int ks = 0; ks < 2; ks++) {
    int k0 = ks * 64;
#pragma unroll
    for (int rr = 0; rr < 4; rr++) {
      int c = rr * 256 + tid;
      int row = c >> 3, cc = c & 7;
      int sc = cc ^ (row & 7);
      size_t goff = ((size_t)row * E_DIM + k0 + sc * 8) * 2;
      int loff = (rr * 256 + (w << 6)) * 16;
      gload_lds16(gA + goff, sA + loff);
      gload_lds16(gB + goff, sB + loff);
    }
    __syncthreads();
#pragma unroll
    for (int kk = 0; kk < 2; kk++) {
      short8 af[4], bfr[4];
#pragma unroll
      for (int m = 0; m < 4; m++) {
        int row = wr + m * 16 + (lane & 15);
        int ch = (kk * 4 + (lane >> 4)) ^ (row & 7);
        af[m] = *(const short8*)(sA + row * 128 + ch * 16);
      }
#pragma unroll
      for (int n = 0; n < 4; n++) {
        int row = wc + n * 16 + (lane & 15);
        int ch = (kk * 4 + (lane >> 4)) ^ (row & 7);
        bfr[n] = *(const short8*)(sB + row * 128 + ch * 16);
      }
#pragma unroll
      for (int m = 0; m < 4; m++)
#pragma unroll
        for (int n = 0; n < 4; n++)
          acc[m][n] = __builtin_amdgcn_mfma_f32_16x16x32_bf16(af[m], bfr[n], acc[m][n], 0, 0, 0);
    }
    __syncthreads();
  }
  float* outp = attn_out + (size_t)bh * S_LEN * S_LEN;
  ushort* Pp = P + (size_t)bh * S_LEN * S_LEN;
#pragma unroll
  for (int m = 0; m < 4; m++) {
#pragma unroll
    for (int ri = 0; ri < 4; ri++) {
      int rl = wr + m * 16 + (lane >> 4) * 4 + ri;
      int sg = tm * 128 + rl;
      float psum = 0.f;
#pragma unroll
      for (int n = 0; n < 4; n++) {
        int tg = tn * 128 + wc + n * 16 + (lane & 15);
        size_t idx = (size_t)sg * S_LEN + tg;
        float av = acc[m][n][ri] * SCALE + resid[idx];
        outp[idx] = av;
        float e = __expf(av);
        psum += e;
        Pp[idx] = f2bf(e * Wepi[idx]);
      }
      // reduce psum across the 16-lane col group
      psum += __shfl_xor(psum, 1);
      psum += __shfl_xor(psum, 2);
      psum += __shfl_xor(psum, 4);
      psum += __shfl_xor(psum, 8);
      if ((lane & 15) == 0) rs_lds[rl][w & 1] = psum;
    }
  }
  __syncthreads();
  if (tid < 128) {
    float s = rs_lds[tid][0] + rs_lds[tid][1];
    rsum[((size_t)bh * S_LEN + tm * 128 + tid) * 16 + tn] = s;
  }
}

// ---------------- K4: effect = (P @ V^T) / l + bo  (clean bf16 GEMM, 64-row tiles) ----------------
__global__ __launch_bounds__(256)
void pv_gemm_kernel(const ushort* __restrict__ P, const ushort* __restrict__ Vt,
                    const float* __restrict__ rsum, const float* __restrict__ bo,
                    float* __restrict__ effect) {
  int tm = blockIdx.x, bh = blockIdx.y;
  int b = bh >> 3, h = bh & 7;
  __shared__ ushort lA[64 * 64];    // P tile: 64 rows x 64 k
  __shared__ ushort lB[128 * 64];   // Vt tile: 128 d x 64 k
  __shared__ float linv_lds[64];
  int tid = threadIdx.x, lane = tid & 63, w = tid >> 6;
  int wr = (w >> 1) * 32, wc = (w & 1) * 64;
  f32x4 acc[2][4] = {};
  // precompute 1/l for this block's 64 rows
  if (tid < 64) {
    const float* rp = rsum + ((size_t)bh * S_LEN + tm * 64 + tid) * 16;
    float s = 0.f;
#pragma unroll
    for (int j = 0; j < 16; j++) s += rp[j];
    linv_lds[tid] = 1.0f / s;
  }
  const char* gA = (const char*)(P + (size_t)bh * S_LEN * S_LEN + (size_t)(tm * 64) * S_LEN);
  const char* gB = (const char*)(Vt + (size_t)bh * HDIM * S_LEN);
  char* sA = (char*)lA;
  char* sB = (char*)lB;
  for (int ks = 0; ks < S_LEN / 64; ks++) {
    int t0 = ks * 64;
#pragma unroll
    for (int rr = 0; rr < 2; rr++) {
      int c = rr * 256 + tid;
      int row = c >> 3, cc = c & 7;
      int sc = cc ^ (row & 7);
      gload_lds16(gA + ((size_t)row * S_LEN + t0 + sc * 8) * 2, sA + (rr * 256 + (w << 6)) * 16);
    }
#pragma unroll
    for (int rr = 0; rr < 4; rr++) {
      int c = rr * 256 + tid;
      int row = c >> 3, cc = c & 7;
      int sc = cc ^ (row & 7);
      gload_lds16(gB + ((size_t)row * S_LEN + t0 + sc * 8) * 2, sB + (rr * 256 + (w << 6)) * 16);
    }
    __syncthreads();
#pragma unroll
    for (int kk = 0; kk < 2; kk++) {
      short8 af[2], bfr[4];
#pragma unroll
      for (int m = 0; m < 2; m++) {
        int row = wr + m * 16 + (lane & 15);
        int ch = (kk * 4 + (lane >> 4)) ^ (row & 7);
        af[m] = *(const short8*)(sA + row * 128 + ch * 16);
      }
#pragma unroll
      for (int n = 0; n < 4; n++) {
        int row = wc + n * 16 + (lane & 15);
        int ch = (kk * 4 + (lane >> 4)) ^ (row & 7);
        bfr[n] = *(const short8*)(sB + row * 128 + ch * 16);
      }
#pragma unroll
      for (int m = 0; m < 2; m++)
#pragma unroll
        for (int n = 0; n < 4; n++)
          acc[m][n] = __builtin_amdgcn_mfma_f32_16x16x32_bf16(af[m], bfr[n], acc[m][n], 0, 0, 0);
    }
    __syncthreads();
  }
#pragma unroll
  for (int m = 0; m < 2; m++) {
#pragma unroll
    for (int ri = 0; ri < 4; ri++) {
      int rl = wr + m * 16 + (lane >> 4) * 4 + ri;
      int sg = tm * 64 + rl;
      float linv = linv_lds[rl];
      float bov = bo[sg];
#pragma unroll
      for (int n = 0; n < 4; n++) {
        int dg = wc + n * 16 + (lane & 15);
        effect[((size_t)(b * S_LEN + sg)) * E_DIM + h * HDIM + dg] = acc[m][n][ri] * linv + bov;
      }
    }
  }
}

extern "C" void kernel_launch(void* const* d_in, const int* in_sizes, int n_in,
                              void* d_out, int out_size, void* d_ws, size_t ws_size,
                              hipStream_t stream) {
  const float* X    = (const float*)d_in[0];
  const float* resd = (const float*)d_in[1];
  const float* Wq   = (const float*)d_in[2];
  const float* Wk   = (const float*)d_in[3];
  const float* Wv   = (const float*)d_in[4];
  const float* Wepi = (const float*)d_in[5];
  const float* bq   = (const float*)d_in[6];
  const float* bk   = (const float*)d_in[7];
  const float* bv   = (const float*)d_in[8];
  const float* bo   = (const float*)d_in[9];

  float* effect = (float*)d_out;
  float* attn   = (float*)d_out + (size_t)2 * S_LEN * E_DIM;

  char* ws = (char*)d_ws;
  ushort* Xb   = (ushort*)(ws);                 //   8,388,608 B
  ushort* WT   = (ushort*)(ws + 8388608);       //   6,291,456 B
  ushort* Qb   = (ushort*)(ws + 14680064);      //   8,388,608 B
  ushort* Kb   = (ushort*)(ws + 23068672);      //   8,388,608 B
  ushort* Vt   = (ushort*)(ws + 31457280);      //   8,388,608 B
  ushort* P    = (ushort*)(ws + 39845888);      // 134,217,728 B
  float*  rsum = (float*)(ws + 174063616);      //   2,097,152 B  (total ~168 MB)

  hipLaunchKernelGGL(cast_x_kernel, dim3(4096), dim3(256), 0, stream, X, Xb);
  hipLaunchKernelGGL(transpose_w_kernel, dim3(16, 16, 3), dim3(256), 0, stream, Wq, Wk, Wv, WT);
  hipLaunchKernelGGL(qkv_gemm_kernel, dim3(32, 8, 3), dim3(256), 0, stream,
                     Xb, WT, bq, bk, bv, Qb, Kb, Vt);
  hipLaunchKernelGGL(attn_gemm_kernel, dim3(16, 16, 16), dim3(256), 0, stream,
                     Qb, Kb, resd, Wepi, attn, P, rsum);
  hipLaunchKernelGGL(pv_gemm_kernel, dim3(32, 16), dim3(256), 0, stream,
                     P, Vt, rsum, bo, effect);
}